// Round 1
// baseline (216.223 us; speedup 1.0000x reference)
//
#include <hip/hip_runtime.h>

typedef short bf16x8 __attribute__((ext_vector_type(8)));
typedef float f32x4 __attribute__((ext_vector_type(4)));

__device__ __forceinline__ unsigned short f2bf(float f) {
    unsigned u = __float_as_uint(f);
    u += 0x7FFFu + ((u >> 16) & 1u);      // round-to-nearest-even
    return (unsigned short)(u >> 16);
}
__device__ __forceinline__ void gload_lds16(const void* g, void* l) {
    __builtin_amdgcn_global_load_lds(
        (const __attribute__((address_space(1))) void*)g,
        (__attribute__((address_space(3))) void*)l,
        16, 0, 0);
}

// ---------------------------------------------------------------- prep (one launch):
// blocks [0,16384): convert u -> bf16 A' with ROW PERMUTATION
//   A'[p*128 + b*16 + ll] = u[b*2048 + p*16 + ll]
// blocks [16384,17408): Bt[j][k] interleaved:  g=j>>5, w=j&31, n=g*16+(w&15)
//   Bt[j][k] = (w<16 ? Br[k][n] : Bi[k][n])          (1024x1024 bf16)
// blocks [17408,18432): Dt[h][j]: Dt[h][j] = (w<16 ? Cr[n][h] : -Ci[n][h])
__global__ void prep(const float* __restrict__ u,
                     const float* __restrict__ Br, const float* __restrict__ Bi,
                     const float* __restrict__ Cr, const float* __restrict__ Ci,
                     unsigned short* __restrict__ A, unsigned short* __restrict__ Bt,
                     unsigned short* __restrict__ Dt) {
    int bid = blockIdx.x;
    if (bid < 16384) {
        int i = bid * 256 + threadIdx.x;        // float4 id, out-order
        int ro = i >> 8, c4 = i & 255;          // out row (permuted), col-group
        int p = ro >> 7, b = (ro >> 4) & 7, ll = ro & 15;
        int ri = b * 2048 + p * 16 + ll;        // source row in u
        float4 v = ((const float4*)u)[(size_t)ri * 256 + c4];
        ushort4 o; o.x = f2bf(v.x); o.y = f2bf(v.y); o.z = f2bf(v.z); o.w = f2bf(v.w);
        ((ushort4*)A)[i] = o;
        return;
    }
    __shared__ unsigned short tile[32][33];
    int id = bid - 16384;          // [0, 2048)
    int z  = id >> 10;             // 0: Bt, 1: Dt
    int t  = id & 1023;
    int jt = t >> 5, kt = t & 31;  // j-tile (32 cols of out), k/h-tile
    int tx = threadIdx.x & 31, ty = threadIdx.x >> 5;   // 32 x 8
    if (z == 0) {
        for (int i2 = ty; i2 < 32; i2 += 8) {          // i2 = k offset
            int k = kt * 32 + i2;
            float v = (tx < 16) ? Br[(size_t)k * 512 + jt * 16 + tx]
                                : Bi[(size_t)k * 512 + jt * 16 + (tx & 15)];
            tile[tx][i2] = f2bf(v);                    // tile[w][k]
        }
        __syncthreads();
        for (int i2 = ty; i2 < 32; i2 += 8)            // i2 = w
            Bt[(size_t)(jt * 32 + i2) * 1024 + kt * 32 + tx] = tile[i2][tx];
    } else {
        for (int i2 = ty; i2 < 32; i2 += 8) {          // i2 = w
            float v = (i2 < 16) ? Cr[(size_t)(jt * 16 + i2) * 1024 + kt * 32 + tx]
                                : -Ci[(size_t)(jt * 16 + (i2 & 15)) * 1024 + kt * 32 + tx];
            tile[i2][tx] = f2bf(v);                    // tile[w][h]
        }
        __syncthreads();
        for (int i2 = ty; i2 < 32; i2 += 8)            // i2 = h offset
            Dt[(size_t)(kt * 32 + i2) * 1024 + jt * 32 + tx] = tile[tx][i2];
    }
}

// ---------------------------------------------------------------- shared K-loop pieces
// 256x256 tile, BK=32, 8 waves (2 x 4), wave tile 128x64, acc[8][4].
// LDS ring: 4 buffers x (A 16KB + B 16KB) = 128 KB.
// T2 swizzle: LDS[row][cb] = G[row][cb ^ ((row&3)<<4)]  (both sides).
// Pipeline: stage t+3 during body t; vmcnt(8) steady (t+2,t+3 in flight), tail 4,0.

#define KLOOP_BODY(AP, BP)                                                          \
    const int tid = threadIdx.x, wave = tid >> 6, lane = tid & 63;                  \
    const int lm = lane & 15, lq = lane >> 4;                                       \
    const int wr = wave >> 2, wc = wave & 3;                                        \
    const int id = blockIdx.x, xcd = id & 7, jb = id >> 3;                          \
    const int T = xcd * 32 + jb;                                                    \
    const int bm = T >> 2, bn = T & 3;                                              \
    const int row0 = bm * 256, col0 = bn * 256;                                     \
    const int r4 = tid >> 2;                                                        \
    const int colb = (((tid & 3) ^ (r4 & 3)) << 4);                                 \
    const char* sA = (const char*)(AP) + (size_t)(row0 + r4) * 2048 + colb;         \
    const char* sB = (const char*)(BP) + (size_t)(col0 + r4) * 2048 + colb;         \
    unsigned short* dA = LDS + tid * 8;                                             \
    unsigned short* dB = LDS + 32768 + tid * 8;                                     \
    const int swz = (lq * 8) ^ ((lm & 3) << 3);                                     \
    const unsigned short* rA = LDS + (wr * 128 + lm) * 32 + swz;                    \
    const unsigned short* rB = LDS + 32768 + (wc * 64 + lm) * 32 + swz;             \
    f32x4 acc[8][4] = {};                                                           \
    STAGE(0, 0); STAGE(1, 1); STAGE(2, 2);                                          \
    asm volatile("s_waitcnt vmcnt(8)");                                             \
    __builtin_amdgcn_s_barrier();                                                   \
    __builtin_amdgcn_sched_barrier(0);                                              \
    _Pragma("unroll 4")                                                             \
    for (int t = 0; t < 32; ++t) {                                                  \
        if (t + 3 < 32) STAGE(t + 3, (t + 3) & 3);                                  \
        const unsigned short* pa = rA + (t & 3) * 8192;                             \
        const unsigned short* pb = rB + (t & 3) * 8192;                             \
        bf16x8 af[8], bfr[4];                                                       \
        _Pragma("unroll")                                                           \
        for (int mi = 0; mi < 8; ++mi) af[mi] = *(const bf16x8*)(pa + mi * 512);    \
        _Pragma("unroll")                                                           \
        for (int ni = 0; ni < 4; ++ni) bfr[ni] = *(const bf16x8*)(pb + ni * 512);   \
        __builtin_amdgcn_s_setprio(1);                                              \
        _Pragma("unroll")                                                           \
        for (int mi = 0; mi < 8; ++mi)                                              \
            _Pragma("unroll")                                                       \
            for (int ni = 0; ni < 4; ++ni)                                          \
                acc[mi][ni] = __builtin_amdgcn_mfma_f32_16x16x32_bf16(              \
                    af[mi], bfr[ni], acc[mi][ni], 0, 0, 0);                         \
        __builtin_amdgcn_s_setprio(0);                                              \
        __builtin_amdgcn_sched_barrier(0);                                          \
        if (t < 29)       asm volatile("s_waitcnt vmcnt(8)");                       \
        else if (t == 29) asm volatile("s_waitcnt vmcnt(4)");                       \
        else if (t == 30) asm volatile("s_waitcnt vmcnt(0)");                       \
        __builtin_amdgcn_s_barrier();                                               \
        __builtin_amdgcn_sched_barrier(0);                                          \
    }

#define STAGE(t_, q_) do {                                                          \
    size_t off_ = (size_t)(t_) * 64;                                                \
    gload_lds16(sA + off_,          dA + (q_) * 8192);                              \
    gload_lds16(sA + off_ + 262144, dA + (q_) * 8192 + 4096);                       \
    gload_lds16(sB + off_,          dB + (q_) * 8192);                              \
    gload_lds16(sB + off_ + 262144, dB + (q_) * 8192 + 4096); } while (0)

// ---------------------------------------------------------------- GEMM1 + fused phase/cumsum
// Wave wr owns l-panel pnl = 2*bm + wr (16 l's x all 8 b): cumsum over b = mi is
// fully in-register per thread. Output X in standard (b*2048+l) rows, interleaved cols.
__global__ __launch_bounds__(512, 2)
void gemm1_fused(const unsigned short* __restrict__ A, const unsigned short* __restrict__ Bt,
                 const int* __restrict__ len, const float* __restrict__ nu_log,
                 const float* __restrict__ th_log, unsigned short* __restrict__ X) {
    __shared__ unsigned short LDS[65536];   // 128 KB
    KLOOP_BODY(A, Bt)

    // ---- fused epilogue: Lambda^e phase multiply + cumsum over b ----
    const float inv2pi = 0.15915494309189535f;
    const float twopi  = 6.283185307179586f;
    int lenv[8];
#pragma unroll
    for (int b = 0; b < 8; ++b) lenv[b] = len[b];
    const int pnl  = 2 * bm + wr;
    const int l_lo = pnl * 16 + lq * 4;
#pragma unroll
    for (int gg = 0; gg < 2; ++gg) {
        const int cbase = col0 + wc * 64 + gg * 32;    // real at +lm, imag at +16+lm
        const int n = (cbase >> 5) * 16 + lm;
        const float nu = __expf(nu_log[n]);
        const float rv = __expf(th_log[n]) * inv2pi;
#pragma unroll
        for (int r = 0; r < 4; ++r) {
            const int l = l_lo + r;
            const float lp1 = (float)(l + 1);
            float sr = 0.f, si = 0.f;
#pragma unroll
            for (int b = 0; b < 8; ++b) {              // b == mi: in-register cumsum
                float e = fmaxf((float)lenv[b] - lp1, 0.f);
                float mag = __expf(-e * nu);
                float ar = e * rv; ar -= floorf(ar);
                float sn, cs; __sincosf(ar * twopi, &sn, &cs);
                float Lr = mag * cs, Li = mag * sn;
                float Bur = acc[b][2 * gg][r], Bui = acc[b][2 * gg + 1][r];
                sr += Lr * Bur - Li * Bui;
                si += Lr * Bui + Li * Bur;
                size_t ro = ((size_t)b * 2048 + l) * 1024;
                X[ro + cbase + lm]      = f2bf(sr);
                X[ro + cbase + lm + 16] = f2bf(si);
            }
        }
    }
}

// ---------------------------------------------------------------- GEMM2: y = X x Dt
__global__ __launch_bounds__(512, 2)
void gemm2(const unsigned short* __restrict__ X, const unsigned short* __restrict__ Dt,
           float* __restrict__ Y) {
    __shared__ unsigned short LDS[65536];   // 128 KB
    KLOOP_BODY(X, Dt)

#pragma unroll
    for (int mi = 0; mi < 8; ++mi) {
#pragma unroll
        for (int ni = 0; ni < 4; ++ni) {
            int c  = col0 + wc * 64 + ni * 16 + lm;
            int r0 = row0 + wr * 128 + mi * 16 + lq * 4;
#pragma unroll
            for (int r = 0; r < 4; ++r)
                Y[(size_t)(r0 + r) * 1024 + c] = acc[mi][ni][r];
        }
    }
}

// ----------------------------------------------------------------
extern "C" void kernel_launch(void* const* d_in, const int* in_sizes, int n_in,
                              void* d_out, int out_size, void* d_ws, size_t ws_size,
                              hipStream_t stream) {
    const float* u      = (const float*)d_in[0];   // (8,2048,1024) f32
    const int*   len    = (const int*)d_in[1];     // (8,)
    const float* nu_log = (const float*)d_in[2];   // (512,)
    const float* th_log = (const float*)d_in[3];   // (512,)
    const float* Br     = (const float*)d_in[4];   // (1024,512)
    const float* Bi     = (const float*)d_in[5];   // (1024,512)
    const float* Cr     = (const float*)d_in[6];   // (512,1024)
    const float* Ci     = (const float*)d_in[7];   // (512,1024)
    float* y = (float*)d_out;                      // (8,2048,1024) f32

    char* ws = (char*)d_ws;
    unsigned short* A  = (unsigned short*)(ws);                 // 32 MB  (u bf16, rows permuted)
    unsigned short* X  = (unsigned short*)(ws + 33554432);      // 32 MB  (phase+cumsum result)
    unsigned short* Bt = (unsigned short*)(ws + 67108864);      //  2 MB
    unsigned short* Dt = (unsigned short*)(ws + 69206016);      //  2 MB

    prep<<<18432, 256, 0, stream>>>(u, Br, Bi, Cr, Ci, A, Bt, Dt);
    gemm1_fused<<<256, 512, 0, stream>>>(A, Bt, len, nu_log, th_log, X);
    gemm2<<<256, 512, 0, stream>>>(X, Dt, y);
}